// Round 2
// baseline (2466.596 us; speedup 1.0000x reference)
//
#include <hip/hip_runtime.h>
#include <cstdint>
#include <cstddef>
#include <math.h>

// ---------------------------------------------------------------------------
// LLM layer (B=1, S=2048, HID=2048, 16 Q heads / 4 KV heads, HD=128, LoRA r=16)
// bf16 MFMA implementation. Workspace requirement: ~286 MB.
// ---------------------------------------------------------------------------

typedef float  f32x4 __attribute__((ext_vector_type(4)));
typedef short  s16x8 __attribute__((ext_vector_type(8)));
typedef unsigned short u16;

#define DI static __device__ __forceinline__

constexpr int S_    = 2048;
constexpr int HID_  = 2048;
constexpr int HD_   = 128;
constexpr int QH_   = 16;
constexpr int KVH_  = 4;
constexpr int QKV_  = 3072;   // (16+8)*128
constexpr int FF_   = 8192;
constexpr int GU2_  = 16384;
constexpr float SCL_ = 0.08838834764831845f; // 1/sqrt(128)

DI u16 f2bf(float x) {
  union { float f; uint32_t u; } v; v.f = x;
  uint32_t r = v.u + 0x7fffu + ((v.u >> 16) & 1u);
  return (u16)(r >> 16);
}
DI float bf2f(u16 s) {
  union { uint32_t u; float f; } v; v.u = ((uint32_t)s) << 16; return v.f;
}

#define MFMA(a, b, c) __builtin_amdgcn_mfma_f32_16x16x32_bf16((a), (b), (c), 0, 0, 0)

// ---------------------------------------------------------------------------
// Transpose + f32->bf16 convert:  in[r][c] (ld=ldin)  ->  out[c][r] (ld=ldout)
// grid = (rows/64, cols/64), block = 256
// ---------------------------------------------------------------------------
__global__ __launch_bounds__(256)
void transpose_cvt_k(const float* __restrict__ in, int ldin,
                     u16* __restrict__ out, int ldout)
{
  __shared__ float tile[64][65];
  const int r0 = blockIdx.x * 64;
  const int c0 = blockIdx.y * 64;
  const int t  = threadIdx.x;
  const int r4 = t >> 6, c = t & 63;
#pragma unroll
  for (int i = 0; i < 16; ++i) {
    int rr = r4 + i * 4;
    tile[rr][c] = in[(size_t)(r0 + rr) * ldin + c0 + c];
  }
  __syncthreads();
#pragma unroll
  for (int i = 0; i < 16; ++i) {
    int rr = r4 + i * 4;
    out[(size_t)(c0 + rr) * ldout + r0 + c] = f2bf(tile[c][rr]);
  }
}

// ---------------------------------------------------------------------------
// RMSNorm: x f32 [S][HID] -> out bf16 [S][HID].  grid=S, block=256
// ---------------------------------------------------------------------------
__global__ __launch_bounds__(256)
void rmsnorm_k(const float* __restrict__ x, const float* __restrict__ w,
               u16* __restrict__ out)
{
  const int m = blockIdx.x, t = threadIdx.x;
  const float* xr = x + (size_t)m * HID_;
  float4 a = *(const float4*)(xr + t * 8);
  float4 b = *(const float4*)(xr + t * 8 + 4);
  float v[8] = {a.x, a.y, a.z, a.w, b.x, b.y, b.z, b.w};
  float ss = 0.f;
#pragma unroll
  for (int e = 0; e < 8; ++e) ss += v[e] * v[e];
#pragma unroll
  for (int off = 32; off; off >>= 1) ss += __shfl_xor(ss, off);
  __shared__ float sm[4];
  if ((t & 63) == 0) sm[t >> 6] = ss;
  __syncthreads();
  const float tot = sm[0] + sm[1] + sm[2] + sm[3];
  const float sc = rsqrtf(tot * (1.0f / HID_) + 1e-6f);
  const float* wr = w + t * 8;
  s16x8 ov;
#pragma unroll
  for (int e = 0; e < 8; ++e) ov[e] = (short)f2bf(v[e] * sc * wr[e]);
  *(s16x8*)(out + (size_t)m * HID_ + t * 8) = ov;
}

// ---------------------------------------------------------------------------
// LoRA-A / gate-logits: out[m][r] = sum_k A_bf16[m][k]*W[k][r] + b[r], r<16
// grid = M, block = 256.  K in {2048, 8192}
// ---------------------------------------------------------------------------
__global__ __launch_bounds__(256)
void lora_a_k(const u16* __restrict__ A, int K,
              const float* __restrict__ W, const float* __restrict__ b,
              float* __restrict__ out)
{
  const int m = blockIdx.x, t = threadIdx.x;
  const int kpt = K >> 8;
  const u16* ar = A + (size_t)m * K + t * kpt;
  float acc[16];
#pragma unroll
  for (int r = 0; r < 16; ++r) acc[r] = 0.f;
  for (int kk = 0; kk < kpt; kk += 8) {
    s16x8 av = *(const s16x8*)(ar + kk);
    const int kbase = t * kpt + kk;
#pragma unroll
    for (int e = 0; e < 8; ++e) {
      float aval = bf2f((u16)av[e]);
      const float* wrow = W + (size_t)(kbase + e) * 16;
      float4 w0 = *(const float4*)(wrow);
      float4 w1 = *(const float4*)(wrow + 4);
      float4 w2 = *(const float4*)(wrow + 8);
      float4 w3 = *(const float4*)(wrow + 12);
      acc[0]  += aval * w0.x; acc[1]  += aval * w0.y; acc[2]  += aval * w0.z; acc[3]  += aval * w0.w;
      acc[4]  += aval * w1.x; acc[5]  += aval * w1.y; acc[6]  += aval * w1.z; acc[7]  += aval * w1.w;
      acc[8]  += aval * w2.x; acc[9]  += aval * w2.y; acc[10] += aval * w2.z; acc[11] += aval * w2.w;
      acc[12] += aval * w3.x; acc[13] += aval * w3.y; acc[14] += aval * w3.z; acc[15] += aval * w3.w;
    }
  }
#pragma unroll
  for (int r = 0; r < 16; ++r)
#pragma unroll
    for (int off = 32; off; off >>= 1) acc[r] += __shfl_xor(acc[r], off);
  __shared__ float sm[64];
  if ((t & 63) == 0) {
#pragma unroll
    for (int r = 0; r < 16; ++r) sm[(t >> 6) * 16 + r] = acc[r];
  }
  __syncthreads();
  if (t < 16)
    out[(size_t)m * 16 + t] = sm[t] + sm[16 + t] + sm[32 + t] + sm[48 + t] + b[t];
}

// ---------------------------------------------------------------------------
// GEMM: C[M][N] = A_bf16[M][K] @ B (Bt = B^T bf16 [N][K]) + bias
//       + 2*(lt[M][16] @ lbw[16][N] + lbb)  (+ res[M][N])
// tile 128 x BN, BK=64, 4 waves, reg-staged prefetch, XOR-swizzled LDS.
// ---------------------------------------------------------------------------
template<int BN, bool OUT_BF, bool HAS_RES>
__global__ __launch_bounds__(256, 2)
void gemm_k(const u16* __restrict__ A, const u16* __restrict__ Bt,
            const float* __restrict__ bias,
            const float* __restrict__ lt, const float* __restrict__ lbw,
            const float* __restrict__ lbb,
            const float* __restrict__ res, void* __restrict__ outp,
            int N, int K)
{
  constexpr int BM = 128, BK = 64;
  constexpr int NJ = BN / 32;                 // n-frags per wave
  constexpr int ACH = 4;                      // (128*64)/(256*8)
  constexpr int BCH = (BN * BK) / (256 * 8);  // 4 or 2
  __shared__ u16 Asm[BM * BK];
  __shared__ u16 Bsm[BN * BK];
  const int tid = threadIdx.x;
  const int lane = tid & 63;
  const int w = tid >> 6;
  const int l15 = lane & 15, g = lane >> 4;
  const int m0 = blockIdx.y * BM, n0 = blockIdx.x * BN;
  const int rm = (w >> 1) * 64, rn = (w & 1) * (BN / 2);

  f32x4 acc[4][NJ];
#pragma unroll
  for (int i = 0; i < 4; ++i)
#pragma unroll
    for (int j = 0; j < NJ; ++j) acc[i][j] = (f32x4){0.f, 0.f, 0.f, 0.f};

  // LoRA rank-16 contribution as one MFMA k-step (k 0..15 real, 16..31 zero).
  {
    s16x8 la[4], lb[NJ];
#pragma unroll
    for (int i = 0; i < 4; ++i) {
      s16x8 v = {0, 0, 0, 0, 0, 0, 0, 0};
      if (g < 2) {
        const float* tp = lt + (size_t)(m0 + rm + i * 16 + l15) * 16 + g * 8;
#pragma unroll
        for (int e = 0; e < 8; ++e) v[e] = (short)f2bf(2.0f * tp[e]);
      }
      la[i] = v;
    }
#pragma unroll
    for (int j = 0; j < NJ; ++j) {
      s16x8 v = {0, 0, 0, 0, 0, 0, 0, 0};
      if (g < 2) {
        const int n = n0 + rn + j * 16 + l15;
#pragma unroll
        for (int e = 0; e < 8; ++e) v[e] = (short)f2bf(lbw[(size_t)(g * 8 + e) * N + n]);
      }
      lb[j] = v;
    }
#pragma unroll
    for (int i = 0; i < 4; ++i)
#pragma unroll
      for (int j = 0; j < NJ; ++j) acc[i][j] = MFMA(la[i], lb[j], acc[i][j]);
  }

  int4 pa[ACH], pb[BCH];
  const int nk = K / BK;
#pragma unroll
  for (int c = 0; c < ACH; ++c) {
    int idx = c * 256 + tid, row = idx >> 3, p = idx & 7;
    pa[c] = *(const int4*)(A + (size_t)(m0 + row) * K + p * 8);
  }
#pragma unroll
  for (int c = 0; c < BCH; ++c) {
    int idx = c * 256 + tid, row = idx >> 3, p = idx & 7;
    pb[c] = *(const int4*)(Bt + (size_t)(n0 + row) * K + p * 8);
  }

  for (int kt = 0; kt < nk; ++kt) {
    __syncthreads();                       // previous compute done reading LDS
#pragma unroll
    for (int c = 0; c < ACH; ++c) {
      int idx = c * 256 + tid, row = idx >> 3, p = idx & 7;
      *(int4*)(Asm + row * BK + ((p ^ (row & 7)) * 8)) = pa[c];
    }
#pragma unroll
    for (int c = 0; c < BCH; ++c) {
      int idx = c * 256 + tid, row = idx >> 3, p = idx & 7;
      *(int4*)(Bsm + row * BK + ((p ^ (row & 7)) * 8)) = pb[c];
    }
    __syncthreads();                       // LDS visible
    if (kt + 1 < nk) {                     // prefetch overlaps compute below
      const int ko = (kt + 1) * BK;
#pragma unroll
      for (int c = 0; c < ACH; ++c) {
        int idx = c * 256 + tid, row = idx >> 3, p = idx & 7;
        pa[c] = *(const int4*)(A + (size_t)(m0 + row) * K + ko + p * 8);
      }
#pragma unroll
      for (int c = 0; c < BCH; ++c) {
        int idx = c * 256 + tid, row = idx >> 3, p = idx & 7;
        pb[c] = *(const int4*)(Bt + (size_t)(n0 + row) * K + ko + p * 8);
      }
    }
#pragma unroll
    for (int ks = 0; ks < 2; ++ks) {
      s16x8 af[4], bfv[NJ];
#pragma unroll
      for (int i = 0; i < 4; ++i) {
        int r = rm + i * 16 + l15;
        af[i] = *(const s16x8*)(Asm + r * BK + (((ks * 4 + g) ^ (r & 7)) * 8));
      }
#pragma unroll
      for (int j = 0; j < NJ; ++j) {
        int r = rn + j * 16 + l15;
        bfv[j] = *(const s16x8*)(Bsm + r * BK + (((ks * 4 + g) ^ (r & 7)) * 8));
      }
#pragma unroll
      for (int i = 0; i < 4; ++i)
#pragma unroll
        for (int j = 0; j < NJ; ++j) acc[i][j] = MFMA(af[i], bfv[j], acc[i][j]);
    }
  }

  // epilogue: + bias + 2*lbb (+res); C/D layout: row=(lane>>4)*4+reg, col=lane&15
#pragma unroll
  for (int j = 0; j < NJ; ++j) {
    const int n = n0 + rn + j * 16 + l15;
    const float bt = bias[n] + 2.0f * lbb[n];
#pragma unroll
    for (int i = 0; i < 4; ++i) {
      const int mb = m0 + rm + i * 16 + g * 4;
#pragma unroll
      for (int reg = 0; reg < 4; ++reg) {
        const size_t o = (size_t)(mb + reg) * N + n;
        float v = acc[i][j][reg] + bt;
        if (HAS_RES) v += res[o];
        if (OUT_BF) ((u16*)outp)[o] = f2bf(v);
        else        ((float*)outp)[o] = v;
      }
    }
  }
}

// ---------------------------------------------------------------------------
// RoPE for q and k: qkv f32 [S][3072] -> qr bf16 [16][S][128], kr bf16 [4][S][128]
// grid = S, block = 256
// ---------------------------------------------------------------------------
__global__ __launch_bounds__(256)
void rope_k(const float* __restrict__ qkv,
            u16* __restrict__ qr, u16* __restrict__ kr)
{
  const int s = blockIdx.x, t = threadIdx.x;
  const float* row = qkv + (size_t)s * QKV_;
#pragma unroll
  for (int p = t; p < 1280; p += 256) {   // 16*64 q-pairs + 4*64 k-pairs
    const int head = p >> 6;
    const int i = p & 63;
    const float freq = expf(-(float)i * (9.210340371976184f / 64.0f));
    const float ang = (float)s * freq;
    float sn, cs;
    sincosf(ang, &sn, &cs);
    int col; u16* dst;
    if (head < QH_) {
      col = head * HD_ + 2 * i;
      dst = qr + ((size_t)head * S_ + s) * HD_ + 2 * i;
    } else {
      const int kh = head - QH_;
      col = QH_ * HD_ + kh * HD_ + 2 * i;
      dst = kr + ((size_t)kh * S_ + s) * HD_ + 2 * i;
    }
    const float x0 = row[col], x1 = row[col + 1];
    const float y0 = x0 * cs - x1 * sn;
    const float y1 = x1 * cs + x0 * sn;
    uint32_t pack = (uint32_t)f2bf(y0) | ((uint32_t)f2bf(y1) << 16);
    *(uint32_t*)dst = pack;
  }
}

// ---------------------------------------------------------------------------
// Flash attention, causal, GQA. 1 wave per (head, 16 q-rows). KVBLK=32.
// Writes gated, normalized output directly as bf16 [S][HID].
// ---------------------------------------------------------------------------
__global__ __launch_bounds__(64, 2)
void attn_k(const u16* __restrict__ qr, const u16* __restrict__ kr,
            const u16* __restrict__ vT, const float* __restrict__ glog,
            u16* __restrict__ valg)
{
  const int h = blockIdx.x, qb = blockIdx.y;
  const int kvh = h >> 2;
  const int lane = threadIdx.x;
  const int l15 = lane & 15, g = lane >> 4;
  const int q0 = qb * 16;
  __shared__ u16 P[16 * 40];    // [16 q][32 kv], padded to 40 (80B rows)

  s16x8 qf[4];
  const u16* qbase = qr + ((size_t)h * S_ + q0 + l15) * HD_ + g * 8;
#pragma unroll
  for (int st = 0; st < 4; ++st) qf[st] = *(const s16x8*)(qbase + st * 32);

  f32x4 oacc[8];
#pragma unroll
  for (int t = 0; t < 8; ++t) oacc[t] = (f32x4){0.f, 0.f, 0.f, 0.f};
  float mrun[4], lrun[4];
#pragma unroll
  for (int r = 0; r < 4; ++r) { mrun[r] = -INFINITY; lrun[r] = 0.f; }

  const u16* krh = kr + (size_t)kvh * S_ * HD_;
  const u16* vth = vT + (size_t)kvh * HD_ * S_;
  const int ktiles = (q0 + 15) / 32 + 1;

  for (int kt = 0; kt < ktiles; ++kt) {
    const int kvb = kt * 32;
    f32x4 s0v = (f32x4){0.f, 0.f, 0.f, 0.f}, s1v = s0v;
#pragma unroll
    for (int st = 0; st < 4; ++st) {
      s16x8 k0 = *(const s16x8*)(krh + (size_t)(kvb + l15) * HD_ + st * 32 + g * 8);
      s16x8 k1 = *(const s16x8*)(krh + (size_t)(kvb + 16 + l15) * HD_ + st * 32 + g * 8);
      s0v = MFMA(qf[st], k0, s0v);
      s1v = MFMA(qf[st], k1, s1v);
    }
    float p0[4], p1[4], mx[4];
#pragma unroll
    for (int r = 0; r < 4; ++r) {
      const int q = q0 + g * 4 + r;
      float a = s0v[r] * SCL_; if (kvb + l15 > q)      a = -1e30f;
      float b = s1v[r] * SCL_; if (kvb + 16 + l15 > q) b = -1e30f;
      p0[r] = a; p1[r] = b; mx[r] = fmaxf(a, b);
    }
#pragma unroll
    for (int r = 0; r < 4; ++r) {
#pragma unroll
      for (int off = 1; off < 16; off <<= 1)
        mx[r] = fmaxf(mx[r], __shfl_xor(mx[r], off));
    }
    float alpha[4];
#pragma unroll
    for (int r = 0; r < 4; ++r) {
      const float mn = fmaxf(mrun[r], mx[r]);
      alpha[r] = expf(mrun[r] - mn);
      const float e0 = expf(p0[r] - mn), e1 = expf(p1[r] - mn);
      p0[r] = e0; p1[r] = e1;
      float ps = e0 + e1;
#pragma unroll
      for (int off = 1; off < 16; off <<= 1) ps += __shfl_xor(ps, off);
      lrun[r] = lrun[r] * alpha[r] + ps;
      mrun[r] = mn;
    }
#pragma unroll
    for (int t = 0; t < 8; ++t)
#pragma unroll
      for (int r = 0; r < 4; ++r) oacc[t][r] *= alpha[r];
    __syncthreads();
#pragma unroll
    for (int r = 0; r < 4; ++r) {
      P[(g * 4 + r) * 40 + l15]      = f2bf(p0[r]);
      P[(g * 4 + r) * 40 + 16 + l15] = f2bf(p1[r]);
    }
    __syncthreads();
    const s16x8 pav = *(const s16x8*)(P + l15 * 40 + g * 8);
#pragma unroll
    for (int t = 0; t < 8; ++t) {
      s16x8 vf = *(const s16x8*)(vth + (size_t)(t * 16 + l15) * S_ + kvb + g * 8);
      oacc[t] = MFMA(pav, vf, oacc[t]);
    }
  }
  float fac[4];
#pragma unroll
  for (int r = 0; r < 4; ++r) {
    const int q = q0 + g * 4 + r;
    const float lg = glog[(size_t)q * 16 + h];
    fac[r] = (1.0f / (1.0f + expf(-lg))) / lrun[r];
  }
#pragma unroll
  for (int t = 0; t < 8; ++t)
#pragma unroll
    for (int r = 0; r < 4; ++r)
      valg[(size_t)(q0 + g * 4 + r) * HID_ + h * HD_ + t * 16 + l15] =
          f2bf(oacc[t][r] * fac[r]);
}

// ---------------------------------------------------------------------------
// gelu(tanh)(gate) * up :  gu bf16 [S][16384] -> hff bf16 [S][8192]
// grid = (4, S), block = 256
// ---------------------------------------------------------------------------
__global__ __launch_bounds__(256)
void gelu_mul_k(const u16* __restrict__ gu, u16* __restrict__ hff)
{
  const int m = blockIdx.y;
  const int j0 = (blockIdx.x * 256 + threadIdx.x) * 8;
  const u16* gp = gu + (size_t)m * GU2_ + j0;
  s16x8 gv = *(const s16x8*)gp;
  s16x8 uv = *(const s16x8*)(gp + FF_);
  s16x8 ov;
#pragma unroll
  for (int e = 0; e < 8; ++e) {
    const float gx = bf2f((u16)gv[e]);
    const float ux = bf2f((u16)uv[e]);
    const float inner = 0.7978845608028654f * (gx + 0.044715f * gx * gx * gx);
    const float hv = 0.5f * gx * (1.0f + tanhf(inner));
    ov[e] = (short)f2bf(hv * ux);
  }
  *(s16x8*)(hff + (size_t)m * FF_ + j0) = ov;
}

// ---------------------------------------------------------------------------
// host-side launch
// ---------------------------------------------------------------------------
extern "C" void kernel_launch(void* const* d_in, const int* in_sizes, int n_in,
                              void* d_out, int out_size, void* d_ws, size_t ws_size,
                              hipStream_t stream)
{
  (void)in_sizes; (void)n_in; (void)out_size; (void)ws_size;
  const float* x     = (const float*)d_in[0];
  const float* n1w   = (const float*)d_in[2];
  const float* n2w   = (const float*)d_in[3];
  const float* qkv_w = (const float*)d_in[4];
  const float* qkv_b = (const float*)d_in[5];
  const float* lqa_w = (const float*)d_in[6];
  const float* lqa_b = (const float*)d_in[7];
  const float* lqb_w = (const float*)d_in[8];
  const float* lqb_b = (const float*)d_in[9];
  const float* o_w   = (const float*)d_in[10];
  const float* o_b   = (const float*)d_in[11];
  const float* loa_w = (const float*)d_in[12];
  const float* loa_b = (const float*)d_in[13];
  const float* lob_w = (const float*)d_in[14];
  const float* lob_b = (const float*)d_in[15];
  const float* gate_w= (const float*)d_in[16];
  const float* gate_b= (const float*)d_in[17];
  const float* gu_w  = (const float*)d_in[18];
  const float* gu_b  = (const float*)d_in[19];
  const float* lga_w = (const float*)d_in[20];
  const float* lga_b = (const float*)d_in[21];
  const float* lgb_w = (const float*)d_in[22];
  const float* lgb_b = (const float*)d_in[23];
  const float* dn_w  = (const float*)d_in[24];
  const float* dn_b  = (const float*)d_in[25];
  const float* lda_w = (const float*)d_in[26];
  const float* lda_b = (const float*)d_in[27];
  const float* ldb_w = (const float*)d_in[28];
  const float* ldb_b = (const float*)d_in[29];

  char* ws = (char*)d_ws;
  constexpr size_t OFF_XN   = 0;                       // bf16 [2048][2048]
  constexpr size_t OFF_WTQ  = OFF_XN   + 8388608;      // bf16 [3072][2048]
  constexpr size_t OFF_WTO  = OFF_WTQ  + 12582912;     // bf16 [2048][2048]
  constexpr size_t OFF_WTG  = OFF_WTO  + 8388608;      // bf16 [16384][2048]
  constexpr size_t OFF_WTD  = OFF_WTG  + 67108864;     // bf16 [2048][8192]
  constexpr size_t OFF_QKV  = OFF_WTD  + 33554432;     // f32  [2048][3072]
  constexpr size_t OFF_QR   = OFF_QKV  + 25165824;     // bf16 [16][2048][128]
  constexpr size_t OFF_KR   = OFF_QR   + 8388608;      // bf16 [4][2048][128]
  constexpr size_t OFF_VT   = OFF_KR   + 2097152;      // bf16 [4][128][2048]
  constexpr size_t OFF_VALG = OFF_VT   + 2097152;      // bf16 [2048][2048]
  constexpr size_t OFF_GU   = OFF_VALG + 8388608;      // bf16 [2048][16384]
  constexpr size_t OFF_HN   = OFF_GU   + 67108864;     // bf16 [2048][2048]
  constexpr size_t OFF_HFF  = OFF_HN   + 8388608;      // bf16 [2048][8192]
  constexpr size_t OFF_TQKV = OFF_HFF  + 33554432;     // f32  [2048][16]
  constexpr size_t OFF_GLOG = OFF_TQKV + 131072;
  constexpr size_t OFF_TO   = OFF_GLOG + 131072;
  constexpr size_t OFF_TGU  = OFF_TO   + 131072;
  constexpr size_t OFF_TDN  = OFF_TGU  + 131072;

  u16*   xn   = (u16*)(ws + OFF_XN);
  u16*   wtq  = (u16*)(ws + OFF_WTQ);
  u16*   wto  = (u16*)(ws + OFF_WTO);
  u16*   wtg  = (u16*)(ws + OFF_WTG);
  u16*   wtd  = (u16*)(ws + OFF_WTD);
  float* qkv  = (float*)(ws + OFF_QKV);
  u16*   qr   = (u16*)(ws + OFF_QR);
  u16*   kr   = (u16*)(ws + OFF_KR);
  u16*   vt   = (u16*)(ws + OFF_VT);
  u16*   valg = (u16*)(ws + OFF_VALG);
  u16*   gub  = (u16*)(ws + OFF_GU);
  u16*   hn   = (u16*)(ws + OFF_HN);
  u16*   hff  = (u16*)(ws + OFF_HFF);
  float* tqkv = (float*)(ws + OFF_TQKV);
  float* glog = (float*)(ws + OFF_GLOG);
  float* t_o  = (float*)(ws + OFF_TO);
  float* t_gu = (float*)(ws + OFF_TGU);
  float* t_dn = (float*)(ws + OFF_TDN);

  // weight transpose + bf16 convert
  transpose_cvt_k<<<dim3(32, 48),  256, 0, stream>>>(qkv_w, QKV_, wtq, HID_);
  transpose_cvt_k<<<dim3(32, 32),  256, 0, stream>>>(o_w,   HID_, wto, HID_);
  transpose_cvt_k<<<dim3(32, 256), 256, 0, stream>>>(gu_w,  GU2_, wtg, HID_);
  transpose_cvt_k<<<dim3(128, 32), 256, 0, stream>>>(dn_w,  HID_, wtd, FF_);

  // attention branch
  rmsnorm_k<<<S_, 256, 0, stream>>>(x, n1w, xn);
  lora_a_k<<<S_, 256, 0, stream>>>(xn, HID_, lqa_w, lqa_b, tqkv);
  lora_a_k<<<S_, 256, 0, stream>>>(xn, HID_, gate_w, gate_b, glog);
  gemm_k<64, false, false><<<dim3(48, 16), 256, 0, stream>>>(
      xn, wtq, qkv_b, tqkv, lqb_w, lqb_b, nullptr, qkv, QKV_, HID_);
  rope_k<<<S_, 256, 0, stream>>>(qkv, qr, kr);
  transpose_cvt_k<<<dim3(32, 8), 256, 0, stream>>>(qkv + 2560, QKV_, vt, S_);
  attn_k<<<dim3(QH_, S_ / 16), 64, 0, stream>>>(qr, kr, vt, glog, valg);
  lora_a_k<<<S_, 256, 0, stream>>>(valg, HID_, loa_w, loa_b, t_o);
  gemm_k<64, false, true><<<dim3(32, 16), 256, 0, stream>>>(
      valg, wto, o_b, t_o, lob_w, lob_b, x, d_out, HID_, HID_);  // h -> d_out

  // feedforward branch
  rmsnorm_k<<<S_, 256, 0, stream>>>((const float*)d_out, n2w, hn);
  lora_a_k<<<S_, 256, 0, stream>>>(hn, HID_, lga_w, lga_b, t_gu);
  gemm_k<128, true, false><<<dim3(128, 16), 256, 0, stream>>>(
      hn, wtg, gu_b, t_gu, lgb_w, lgb_b, nullptr, gub, GU2_, HID_);
  gelu_mul_k<<<dim3(4, S_), 256, 0, stream>>>(gub, hff);
  lora_a_k<<<S_, 256, 0, stream>>>(hff, FF_, lda_w, lda_b, t_dn);
  gemm_k<64, false, true><<<dim3(32, 16), 256, 0, stream>>>(
      hff, wtd, dn_b, t_dn, ldb_w, ldb_b, (const float*)d_out, d_out, HID_, FF_);
}

// Round 4
// 1290.358 us; speedup vs baseline: 1.9116x; 1.9116x over previous
//
#include <hip/hip_runtime.h>
#include <cstdint>
#include <cstddef>
#include <math.h>

// ---------------------------------------------------------------------------
// LLM layer (B=1, S=2048, HID=2048, 16 Q heads / 4 KV heads, HD=128, LoRA r=16)
// bf16 MFMA implementation. Workspace requirement: ~286 MB.
// R3: GEMM staging via global_load_lds (width=16), pre-swizzled source,
//     no reg prefetch (fixes the 2 GB/dispatch scratch-spill traffic seen in
//     R2: VGPR_Count=68 with a ~200-reg working set), XCD-aware block swizzle.
// ---------------------------------------------------------------------------

typedef float  f32x4 __attribute__((ext_vector_type(4)));
typedef short  s16x8 __attribute__((ext_vector_type(8)));
typedef unsigned short u16;

#define DI static __device__ __forceinline__

constexpr int S_    = 2048;
constexpr int HID_  = 2048;
constexpr int HD_   = 128;
constexpr int QH_   = 16;
constexpr int KVH_  = 4;
constexpr int QKV_  = 3072;   // (16+8)*128
constexpr int FF_   = 8192;
constexpr int GU2_  = 16384;
constexpr float SCL_ = 0.08838834764831845f; // 1/sqrt(128)

DI u16 f2bf(float x) {
  union { float f; uint32_t u; } v; v.f = x;
  uint32_t r = v.u + 0x7fffu + ((v.u >> 16) & 1u);
  return (u16)(r >> 16);
}
DI float bf2f(u16 s) {
  union { uint32_t u; float f; } v; v.u = ((uint32_t)s) << 16; return v.f;
}

#define MFMA(a, b, c) __builtin_amdgcn_mfma_f32_16x16x32_bf16((a), (b), (c), 0, 0, 0)

// async global->LDS, 16 bytes per lane, wave-uniform LDS base (lane*16 applied by HW)
DI void gload_lds16(const u16* g, u16* l) {
  __builtin_amdgcn_global_load_lds(
      (const __attribute__((address_space(1))) uint32_t*)g,
      (__attribute__((address_space(3))) uint32_t*)l,
      16, 0, 0);
}

// ---------------------------------------------------------------------------
// Transpose + f32->bf16 convert:  in[r][c] (ld=ldin)  ->  out[c][r] (ld=ldout)
// grid = (rows/64, cols/64), block = 256
// ---------------------------------------------------------------------------
__global__ __launch_bounds__(256)
void transpose_cvt_k(const float* __restrict__ in, int ldin,
                     u16* __restrict__ out, int ldout)
{
  __shared__ float tile[64][65];
  const int r0 = blockIdx.x * 64;
  const int c0 = blockIdx.y * 64;
  const int t  = threadIdx.x;
  const int r4 = t >> 6, c = t & 63;
#pragma unroll
  for (int i = 0; i < 16; ++i) {
    int rr = r4 + i * 4;
    tile[rr][c] = in[(size_t)(r0 + rr) * ldin + c0 + c];
  }
  __syncthreads();
#pragma unroll
  for (int i = 0; i < 16; ++i) {
    int rr = r4 + i * 4;
    out[(size_t)(c0 + rr) * ldout + r0 + c] = f2bf(tile[c][rr]);
  }
}

// ---------------------------------------------------------------------------
// RMSNorm: x f32 [S][HID] -> out bf16 [S][HID].  grid=S, block=256
// ---------------------------------------------------------------------------
__global__ __launch_bounds__(256)
void rmsnorm_k(const float* __restrict__ x, const float* __restrict__ w,
               u16* __restrict__ out)
{
  const int m = blockIdx.x, t = threadIdx.x;
  const float* xr = x + (size_t)m * HID_;
  float4 a = *(const float4*)(xr + t * 8);
  float4 b = *(const float4*)(xr + t * 8 + 4);
  float v[8] = {a.x, a.y, a.z, a.w, b.x, b.y, b.z, b.w};
  float ss = 0.f;
#pragma unroll
  for (int e = 0; e < 8; ++e) ss += v[e] * v[e];
#pragma unroll
  for (int off = 32; off; off >>= 1) ss += __shfl_xor(ss, off);
  __shared__ float sm[4];
  if ((t & 63) == 0) sm[t >> 6] = ss;
  __syncthreads();
  const float tot = sm[0] + sm[1] + sm[2] + sm[3];
  const float sc = rsqrtf(tot * (1.0f / HID_) + 1e-6f);
  const float* wr = w + t * 8;
  s16x8 ov;
#pragma unroll
  for (int e = 0; e < 8; ++e) ov[e] = (short)f2bf(v[e] * sc * wr[e]);
  *(s16x8*)(out + (size_t)m * HID_ + t * 8) = ov;
}

// ---------------------------------------------------------------------------
// LoRA-A / gate-logits: out[m][r] = sum_k A_bf16[m][k]*W[k][r] + b[r], r<16
// grid = M, block = 256.  K in {2048, 8192}
// ---------------------------------------------------------------------------
__global__ __launch_bounds__(256)
void lora_a_k(const u16* __restrict__ A, int K,
              const float* __restrict__ W, const float* __restrict__ b,
              float* __restrict__ out)
{
  const int m = blockIdx.x, t = threadIdx.x;
  const int kpt = K >> 8;
  const u16* ar = A + (size_t)m * K + t * kpt;
  float acc[16];
#pragma unroll
  for (int r = 0; r < 16; ++r) acc[r] = 0.f;
  for (int kk = 0; kk < kpt; kk += 8) {
    s16x8 av = *(const s16x8*)(ar + kk);
    const int kbase = t * kpt + kk;
#pragma unroll
    for (int e = 0; e < 8; ++e) {
      float aval = bf2f((u16)av[e]);
      const float* wrow = W + (size_t)(kbase + e) * 16;
      float4 w0 = *(const float4*)(wrow);
      float4 w1 = *(const float4*)(wrow + 4);
      float4 w2 = *(const float4*)(wrow + 8);
      float4 w3 = *(const float4*)(wrow + 12);
      acc[0]  += aval * w0.x; acc[1]  += aval * w0.y; acc[2]  += aval * w0.z; acc[3]  += aval * w0.w;
      acc[4]  += aval * w1.x; acc[5]  += aval * w1.y; acc[6]  += aval * w1.z; acc[7]  += aval * w1.w;
      acc[8]  += aval * w2.x; acc[9]  += aval * w2.y; acc[10] += aval * w2.z; acc[11] += aval * w2.w;
      acc[12] += aval * w3.x; acc[13] += aval * w3.y; acc[14] += aval * w3.z; acc[15] += aval * w3.w;
    }
  }
#pragma unroll
  for (int r = 0; r < 16; ++r)
#pragma unroll
    for (int off = 32; off; off >>= 1) acc[r] += __shfl_xor(acc[r], off);
  __shared__ float sm[64];
  if ((t & 63) == 0) {
#pragma unroll
    for (int r = 0; r < 16; ++r) sm[(t >> 6) * 16 + r] = acc[r];
  }
  __syncthreads();
  if (t < 16)
    out[(size_t)m * 16 + t] = sm[t] + sm[16 + t] + sm[32 + t] + sm[48 + t] + b[t];
}

// ---------------------------------------------------------------------------
// GEMM: C[M][N] = A_bf16[M][K] @ B (Bt = B^T bf16 [N][K]) + bias
//       + 2*(lt[M][16] @ lbw[16][N] + lbb)  (+ res[M][N])
// tile 128 x BN, BK=64, 4 waves.
// Staging: global_load_lds x16B, linear LDS dest, PRE-SWIZZLED global source
// (chunk slot = (lane&7)^(lane>>3)); read side uses slot^(row&7) -> both
// permutations match (rule #21), ds_read_b128 is bank-conflict-free.
// ---------------------------------------------------------------------------
template<int BN, bool OUT_BF, bool HAS_RES>
__global__ __launch_bounds__(256)
void gemm_k(const u16* __restrict__ A, const u16* __restrict__ Bt,
            const float* __restrict__ bias,
            const float* __restrict__ lt, const float* __restrict__ lbw,
            const float* __restrict__ lbb,
            const float* __restrict__ res, void* __restrict__ outp,
            int N, int K)
{
  constexpr int BM = 128, BK = 64;
  constexpr int NJ = BN / 32;                 // n-frags per wave
  constexpr int BCW = BN / 32;                // B chunks per wave (4 or 2)
  __shared__ u16 Asm[BM * BK];
  __shared__ u16 Bsm[BN * BK];
  const int tid = threadIdx.x;
  const int lane = tid & 63;
  const int w = tid >> 6;
  const int l15 = lane & 15, g = lane >> 4;

  // XCD-aware bijective block swizzle (all grids have nwg % 8 == 0):
  // XCD x receives a contiguous tile range -> A-panel reuse in its L2.
  const int nwg = gridDim.x * gridDim.y;
  const int linear = blockIdx.y * gridDim.x + blockIdx.x;
  const int tile = (linear & 7) * (nwg >> 3) + (linear >> 3);
  const int bx = tile % gridDim.x;
  const int by = tile / gridDim.x;
  const int m0 = by * BM, n0 = bx * BN;
  const int rm = (w >> 1) * 64, rn = (w & 1) * (BN / 2);

  f32x4 acc[4][NJ];
#pragma unroll
  for (int i = 0; i < 4; ++i)
#pragma unroll
    for (int j = 0; j < NJ; ++j) acc[i][j] = (f32x4){0.f, 0.f, 0.f, 0.f};

  // LoRA rank-16 contribution as one MFMA k-step (k 0..15 real, 16..31 zero).
  {
    s16x8 la[4], lb[NJ];
#pragma unroll
    for (int i = 0; i < 4; ++i) {
      s16x8 v = {0, 0, 0, 0, 0, 0, 0, 0};
      if (g < 2) {
        const float* tp = lt + (size_t)(m0 + rm + i * 16 + l15) * 16 + g * 8;
#pragma unroll
        for (int e = 0; e < 8; ++e) v[e] = (short)f2bf(2.0f * tp[e]);
      }
      la[i] = v;
    }
#pragma unroll
    for (int j = 0; j < NJ; ++j) {
      s16x8 v = {0, 0, 0, 0, 0, 0, 0, 0};
      if (g < 2) {
        const int n = n0 + rn + j * 16 + l15;
#pragma unroll
        for (int e = 0; e < 8; ++e) v[e] = (short)f2bf(lbw[(size_t)(g * 8 + e) * N + n]);
      }
      lb[j] = v;
    }
#pragma unroll
    for (int i = 0; i < 4; ++i)
#pragma unroll
      for (int j = 0; j < NJ; ++j) acc[i][j] = MFMA(la[i], lb[j], acc[i][j]);
  }

  // Staging geometry: 1 KiB chunk = 8 rows x 64 u16. A: 16 chunks, 4/wave.
  // Lane covers (row = chunk*8 + (lane>>3), global slot = (lane&7)^(lane>>3)),
  // lands linearly at LDS chunk_base + lane*16B  ->  LDS(r,s) = glob(r, s^(r&7)).
  const int srow  = lane >> 3;
  const int sslot = (lane & 7) ^ srow;
  const u16* Aga[4];
  u16* Alds[4];
#pragma unroll
  for (int c = 0; c < 4; ++c) {
    const int ch = w * 4 + c;
    Aga[c]  = A + (size_t)(m0 + ch * 8 + srow) * K + sslot * 8;
    Alds[c] = Asm + ch * 512;
  }
  const u16* Bga[BCW];
  u16* Blds[BCW];
#pragma unroll
  for (int c = 0; c < BCW; ++c) {
    const int ch = w * BCW + c;
    Bga[c]  = Bt + (size_t)(n0 + ch * 8 + srow) * K + sslot * 8;
    Blds[c] = Bsm + ch * 512;
  }

  const int nk = K / BK;
  for (int kt = 0; kt < nk; ++kt) {
    const int ko = kt * BK;
    __syncthreads();                       // all waves done reading LDS
#pragma unroll
    for (int c = 0; c < 4; ++c)   gload_lds16(Aga[c] + ko, Alds[c]);
#pragma unroll
    for (int c = 0; c < BCW; ++c) gload_lds16(Bga[c] + ko, Blds[c]);
    __syncthreads();                       // vmcnt(0) drain + barrier: LDS ready
#pragma unroll
    for (int ks = 0; ks < 2; ++ks) {
      s16x8 af[4], bfv[NJ];
#pragma unroll
      for (int i = 0; i < 4; ++i) {
        int r = rm + i * 16 + l15;
        af[i] = *(const s16x8*)(Asm + r * BK + (((ks * 4 + g) ^ (r & 7)) * 8));
      }
#pragma unroll
      for (int j = 0; j < NJ; ++j) {
        int r = rn + j * 16 + l15;
        bfv[j] = *(const s16x8*)(Bsm + r * BK + (((ks * 4 + g) ^ (r & 7)) * 8));
      }
#pragma unroll
      for (int i = 0; i < 4; ++i)
#pragma unroll
        for (int j = 0; j < NJ; ++j) acc[i][j] = MFMA(af[i], bfv[j], acc[i][j]);
    }
  }

  // epilogue: + bias + 2*lbb (+res); C/D layout: row=(lane>>4)*4+reg, col=lane&15
#pragma unroll
  for (int j = 0; j < NJ; ++j) {
    const int n = n0 + rn + j * 16 + l15;
    const float bt = bias[n] + 2.0f * lbb[n];
#pragma unroll
    for (int i = 0; i < 4; ++i) {
      const int mb = m0 + rm + i * 16 + g * 4;
#pragma unroll
      for (int reg = 0; reg < 4; ++reg) {
        const size_t o = (size_t)(mb + reg) * N + n;
        float v = acc[i][j][reg] + bt;
        if (HAS_RES) v += res[o];
        if (OUT_BF) ((u16*)outp)[o] = f2bf(v);
        else        ((float*)outp)[o] = v;
      }
    }
  }
}

// ---------------------------------------------------------------------------
// RoPE for q and k: qkv f32 [S][3072] -> qr bf16 [16][S][128], kr bf16 [4][S][128]
// grid = S, block = 256
// ---------------------------------------------------------------------------
__global__ __launch_bounds__(256)
void rope_k(const float* __restrict__ qkv,
            u16* __restrict__ qr, u16* __restrict__ kr)
{
  const int s = blockIdx.x, t = threadIdx.x;
  const float* row = qkv + (size_t)s * QKV_;
#pragma unroll
  for (int p = t; p < 1280; p += 256) {   // 16*64 q-pairs + 4*64 k-pairs
    const int head = p >> 6;
    const int i = p & 63;
    const float freq = expf(-(float)i * (9.210340371976184f / 64.0f));
    const float ang = (float)s * freq;
    float sn, cs;
    sincosf(ang, &sn, &cs);
    int col; u16* dst;
    if (head < QH_) {
      col = head * HD_ + 2 * i;
      dst = qr + ((size_t)head * S_ + s) * HD_ + 2 * i;
    } else {
      const int kh = head - QH_;
      col = QH_ * HD_ + kh * HD_ + 2 * i;
      dst = kr + ((size_t)kh * S_ + s) * HD_ + 2 * i;
    }
    const float x0 = row[col], x1 = row[col + 1];
    const float y0 = x0 * cs - x1 * sn;
    const float y1 = x1 * cs + x0 * sn;
    uint32_t pack = (uint32_t)f2bf(y0) | ((uint32_t)f2bf(y1) << 16);
    *(uint32_t*)dst = pack;
  }
}

// ---------------------------------------------------------------------------
// Flash attention, causal, GQA. 1 wave per (head, 16 q-rows). KVBLK=32.
// Writes gated, normalized output directly as bf16 [S][HID].
// ---------------------------------------------------------------------------
__global__ __launch_bounds__(64, 2)
void attn_k(const u16* __restrict__ qr, const u16* __restrict__ kr,
            const u16* __restrict__ vT, const float* __restrict__ glog,
            u16* __restrict__ valg)
{
  const int h = blockIdx.x, qb = blockIdx.y;
  const int kvh = h >> 2;
  const int lane = threadIdx.x;
  const int l15 = lane & 15, g = lane >> 4;
  const int q0 = qb * 16;
  __shared__ u16 P[16 * 40];    // [16 q][32 kv], padded to 40 (80B rows)

  s16x8 qf[4];
  const u16* qbase = qr + ((size_t)h * S_ + q0 + l15) * HD_ + g * 8;
#pragma unroll
  for (int st = 0; st < 4; ++st) qf[st] = *(const s16x8*)(qbase + st * 32);

  f32x4 oacc[8];
#pragma unroll
  for (int t = 0; t < 8; ++t) oacc[t] = (f32x4){0.f, 0.f, 0.f, 0.f};
  float mrun[4], lrun[4];
#pragma unroll
  for (int r = 0; r < 4; ++r) { mrun[r] = -INFINITY; lrun[r] = 0.f; }

  const u16* krh = kr + (size_t)kvh * S_ * HD_;
  const u16* vth = vT + (size_t)kvh * HD_ * S_;
  const int ktiles = (q0 + 15) / 32 + 1;

  for (int kt = 0; kt < ktiles; ++kt) {
    const int kvb = kt * 32;
    f32x4 s0v = (f32x4){0.f, 0.f, 0.f, 0.f}, s1v = s0v;
#pragma unroll
    for (int st = 0; st < 4; ++st) {
      s16x8 k0 = *(const s16x8*)(krh + (size_t)(kvb + l15) * HD_ + st * 32 + g * 8);
      s16x8 k1 = *(const s16x8*)(krh + (size_t)(kvb + 16 + l15) * HD_ + st * 32 + g * 8);
      s0v = MFMA(qf[st], k0, s0v);
      s1v = MFMA(qf[st], k1, s1v);
    }
    float p0[4], p1[4], mx[4];
#pragma unroll
    for (int r = 0; r < 4; ++r) {
      const int q = q0 + g * 4 + r;
      float a = s0v[r] * SCL_; if (kvb + l15 > q)      a = -1e30f;
      float b = s1v[r] * SCL_; if (kvb + 16 + l15 > q) b = -1e30f;
      p0[r] = a; p1[r] = b; mx[r] = fmaxf(a, b);
    }
#pragma unroll
    for (int r = 0; r < 4; ++r) {
#pragma unroll
      for (int off = 1; off < 16; off <<= 1)
        mx[r] = fmaxf(mx[r], __shfl_xor(mx[r], off));
    }
    float alpha[4];
#pragma unroll
    for (int r = 0; r < 4; ++r) {
      const float mn = fmaxf(mrun[r], mx[r]);
      alpha[r] = expf(mrun[r] - mn);
      const float e0 = expf(p0[r] - mn), e1 = expf(p1[r] - mn);
      p0[r] = e0; p1[r] = e1;
      float ps = e0 + e1;
#pragma unroll
      for (int off = 1; off < 16; off <<= 1) ps += __shfl_xor(ps, off);
      lrun[r] = lrun[r] * alpha[r] + ps;
      mrun[r] = mn;
    }
#pragma unroll
    for (int t = 0; t < 8; ++t)
#pragma unroll
      for (int r = 0; r < 4; ++r) oacc[t][r] *= alpha[r];
    __syncthreads();
#pragma unroll
    for (int r = 0; r < 4; ++r) {
      P[(g * 4 + r) * 40 + l15]      = f2bf(p0[r]);
      P[(g * 4 + r) * 40 + 16 + l15] = f2bf(p1[r]);
    }
    __syncthreads();
    const s16x8 pav = *(const s16x8*)(P + l15 * 40 + g * 8);
#pragma unroll
    for (int t = 0; t < 8; ++t) {
      s16x8 vf = *(const s16x8*)(vth + (size_t)(t * 16 + l15) * S_ + kvb + g * 8);
      oacc[t] = MFMA(pav, vf, oacc[t]);
    }
  }
  float fac[4];
#pragma unroll
  for (int r = 0; r < 4; ++r) {
    const int q = q0 + g * 4 + r;
    const float lg = glog[(size_t)q * 16 + h];
    fac[r] = (1.0f / (1.0f + expf(-lg))) / lrun[r];
  }
#pragma unroll
  for (int t = 0; t < 8; ++t)
#pragma unroll
    for (int r = 0; r < 4; ++r)
      valg[(size_t)(q0 + g * 4 + r) * HID_ + h * HD_ + t * 16 + l15] =
          f2bf(oacc[t][r] * fac[r]);
}

// ---------------------------------------------------------------------------
// gelu(tanh)(gate) * up :  gu bf16 [S][16384] -> hff bf16 [S][8192]
// grid = (4, S), block = 256
// ---------------------------------------------------------------------------
__global__ __launch_bounds__(256)
void gelu_mul_k(const u16* __restrict__ gu, u16* __restrict__ hff)
{
  const int m = blockIdx.y;
  const int j0 = (blockIdx.x * 256 + threadIdx.x) * 8;
  const u16* gp = gu + (size_t)m * GU2_ + j0;
  s16x8 gv = *(const s16x8*)gp;
  s16x8 uv = *(const s16x8*)(gp + FF_);
  s16x8 ov;
#pragma unroll
  for (int e = 0; e < 8; ++e) {
    const float gx = bf2f((u16)gv[e]);
    const float ux = bf2f((u16)uv[e]);
    const float inner = 0.7978845608028654f * (gx + 0.044715f * gx * gx * gx);
    const float hv = 0.5f * gx * (1.0f + tanhf(inner));
    ov[e] = (short)f2bf(hv * ux);
  }
  *(s16x8*)(hff + (size_t)m * FF_ + j0) = ov;
}

// ---------------------------------------------------------------------------
// host-side launch
// ---------------------------------------------------------------------------
extern "C" void kernel_launch(void* const* d_in, const int* in_sizes, int n_in,
                              void* d_out, int out_size, void* d_ws, size_t ws_size,
                              hipStream_t stream)
{
  (void)in_sizes; (void)n_in; (void)out_size; (void)ws_size;
  const float* x     = (const float*)d_in[0];
  const float* n1w   = (const float*)d_in[2];
  const float* n2w   = (const float*)d_in[3];
  const float* qkv_w = (const float*)d_in[4];
  const float* qkv_b = (const float*)d_in[5];
  const float* lqa_w = (const float*)d_in[6];
  const float* lqa_b = (const float*)d_in[7];
  const float* lqb_w = (const float*)d_in[8];
  const float* lqb_b = (const float*)d_in[9];
  const float* o_w   = (const float*)d_in[10];
  const float* o_b   = (const float*)d_in[11];
  const float* loa_w = (const float*)d_in[12];
  const float* loa_b = (const float*)d_in[13];
  const float* lob_w = (const float*)d_in[14];
  const float* lob_b = (const float*)d_in[15];
  const float* gate_w= (const float*)d_in[16];
  const float* gate_b= (const float*)d_in[17];
  const float* gu_w  = (const float*)d_in[18];
  const float* gu_b  = (const float*)d_in[19];
  const float* lga_w = (const float*)d_in[20];
  const float* lga_b = (const float*)d_in[21];
  const float* lgb_w = (const float*)d_in[22];
  const float* lgb_b = (const float*)d_in[23];
  const float* dn_w  = (const float*)d_in[24];
  const float* dn_b  = (const float*)d_in[25];
  const float* lda_w = (const float*)d_in[26];
  const float* lda_b = (const float*)d_in[27];
  const float* ldb_w = (const float*)d_in[28];
  const float* ldb_b = (const float*)d_in[29];

  char* ws = (char*)d_ws;
  constexpr size_t OFF_XN   = 0;                       // bf16 [2048][2048]
  constexpr size_t OFF_WTQ  = OFF_XN   + 8388608;      // bf16 [3072][2048]
  constexpr size_t OFF_WTO  = OFF_WTQ  + 12582912;     // bf16 [2048][2048]
  constexpr size_t OFF_WTG  = OFF_WTO  + 8388608;      // bf16 [16384][2048]
  constexpr size_t OFF_WTD  = OFF_WTG  + 67108864;     // bf16 [2048][8192]
  constexpr size_t OFF_QKV  = OFF_WTD  + 33554432;     // f32  [2048][3072]
  constexpr size_t OFF_QR   = OFF_QKV  + 25165824;     // bf16 [16][2048][128]
  constexpr size_t OFF_KR   = OFF_QR   + 8388608;      // bf16 [4][2048][128]
  constexpr size_t OFF_VT   = OFF_KR   + 2097152;      // bf16 [4][128][2048]
  constexpr size_t OFF_VALG = OFF_VT   + 2097152;      // bf16 [2048][2048]
  constexpr size_t OFF_GU   = OFF_VALG + 8388608;      // bf16 [2048][16384]
  constexpr size_t OFF_HN   = OFF_GU   + 67108864;     // bf16 [2048][2048]
  constexpr size_t OFF_HFF  = OFF_HN   + 8388608;      // bf16 [2048][8192]
  constexpr size_t OFF_TQKV = OFF_HFF  + 33554432;     // f32  [2048][16]
  constexpr size_t OFF_GLOG = OFF_TQKV + 131072;
  constexpr size_t OFF_TO   = OFF_GLOG + 131072;
  constexpr size_t OFF_TGU  = OFF_TO   + 131072;
  constexpr size_t OFF_TDN  = OFF_TGU  + 131072;

  u16*   xn   = (u16*)(ws + OFF_XN);
  u16*   wtq  = (u16*)(ws + OFF_WTQ);
  u16*   wto  = (u16*)(ws + OFF_WTO);
  u16*   wtg  = (u16*)(ws + OFF_WTG);
  u16*   wtd  = (u16*)(ws + OFF_WTD);
  float* qkv  = (float*)(ws + OFF_QKV);
  u16*   qr   = (u16*)(ws + OFF_QR);
  u16*   kr   = (u16*)(ws + OFF_KR);
  u16*   vt   = (u16*)(ws + OFF_VT);
  u16*   valg = (u16*)(ws + OFF_VALG);
  u16*   gub  = (u16*)(ws + OFF_GU);
  u16*   hn   = (u16*)(ws + OFF_HN);
  u16*   hff  = (u16*)(ws + OFF_HFF);
  float* tqkv = (float*)(ws + OFF_TQKV);
  float* glog = (float*)(ws + OFF_GLOG);
  float* t_o  = (float*)(ws + OFF_TO);
  float* t_gu = (float*)(ws + OFF_TGU);
  float* t_dn = (float*)(ws + OFF_TDN);

  // weight transpose + bf16 convert
  transpose_cvt_k<<<dim3(32, 48),  256, 0, stream>>>(qkv_w, QKV_, wtq, HID_);
  transpose_cvt_k<<<dim3(32, 32),  256, 0, stream>>>(o_w,   HID_, wto, HID_);
  transpose_cvt_k<<<dim3(32, 256), 256, 0, stream>>>(gu_w,  GU2_, wtg, HID_);
  transpose_cvt_k<<<dim3(128, 32), 256, 0, stream>>>(dn_w,  HID_, wtd, FF_);

  // attention branch
  rmsnorm_k<<<S_, 256, 0, stream>>>(x, n1w, xn);
  lora_a_k<<<S_, 256, 0, stream>>>(xn, HID_, lqa_w, lqa_b, tqkv);
  lora_a_k<<<S_, 256, 0, stream>>>(xn, HID_, gate_w, gate_b, glog);
  gemm_k<64, false, false><<<dim3(48, 16), 256, 0, stream>>>(
      xn, wtq, qkv_b, tqkv, lqb_w, lqb_b, nullptr, qkv, QKV_, HID_);
  rope_k<<<S_, 256, 0, stream>>>(qkv, qr, kr);
  transpose_cvt_k<<<dim3(32, 8), 256, 0, stream>>>(qkv + 2560, QKV_, vt, S_);
  attn_k<<<dim3(QH_, S_ / 16), 64, 0, stream>>>(qr, kr, vt, glog, valg);
  lora_a_k<<<S_, 256, 0, stream>>>(valg, HID_, loa_w, loa_b, t_o);
  gemm_k<64, false, true><<<dim3(32, 16), 256, 0, stream>>>(
      valg, wto, o_b, t_o, lob_w, lob_b, x, d_out, HID_, HID_);  // h -> d_out

  // feedforward branch
  rmsnorm_k<<<S_, 256, 0, stream>>>((const float*)d_out, n2w, hn);
  lora_a_k<<<S_, 256, 0, stream>>>(hn, HID_, lga_w, lga_b, t_gu);
  gemm_k<128, true, false><<<dim3(128, 16), 256, 0, stream>>>(
      hn, wtg, gu_b, t_gu, lgb_w, lgb_b, nullptr, gub, GU2_, HID_);
  gelu_mul_k<<<dim3(4, S_), 256, 0, stream>>>(gub, hff);
  lora_a_k<<<S_, 256, 0, stream>>>(hff, FF_, lda_w, lda_b, t_dn);
  gemm_k<64, false, true><<<dim3(32, 16), 256, 0, stream>>>(
      hff, wtd, dn_b, t_dn, ldb_w, ldb_b, (const float*)d_out, d_out, HID_, FF_);
}

// Round 8
// 1012.459 us; speedup vs baseline: 2.4362x; 1.2745x over previous
//
#include <hip/hip_runtime.h>
#include <cstdint>
#include <cstddef>
#include <math.h>

// ---------------------------------------------------------------------------
// LLM layer (B=1, S=2048, HID=2048, 16 Q heads / 4 KV heads, HD=128, LoRA r=16)
// bf16 MFMA implementation. Workspace requirement: ~274 MB.
// R3: GEMM staging via global_load_lds (width=16), pre-swizzled source.
// R5: lora_a_k was 5x197us = 76% of runtime, transaction-bound on the
//     stride-512B W gather (64 cache lines per load instr). Fix: pre-transpose
//     lora-A/gate weights to Wt[16][K] bf16; all loads now coalesced 16B/lane.
// ---------------------------------------------------------------------------

typedef float  f32x4 __attribute__((ext_vector_type(4)));
typedef short  s16x8 __attribute__((ext_vector_type(8)));
typedef short  s16x4 __attribute__((ext_vector_type(4)));
typedef unsigned short u16;

#define DI static __device__ __forceinline__

constexpr int S_    = 2048;
constexpr int HID_  = 2048;
constexpr int HD_   = 128;
constexpr int QH_   = 16;
constexpr int KVH_  = 4;
constexpr int QKV_  = 3072;   // (16+8)*128
constexpr int FF_   = 8192;
constexpr int GU2_  = 16384;
constexpr float SCL_ = 0.08838834764831845f; // 1/sqrt(128)

DI u16 f2bf(float x) {
  union { float f; uint32_t u; } v; v.f = x;
  uint32_t r = v.u + 0x7fffu + ((v.u >> 16) & 1u);
  return (u16)(r >> 16);
}
DI float bf2f(u16 s) {
  union { uint32_t u; float f; } v; v.u = ((uint32_t)s) << 16; return v.f;
}

#define MFMA(a, b, c) __builtin_amdgcn_mfma_f32_16x16x32_bf16((a), (b), (c), 0, 0, 0)

// async global->LDS, 16 bytes per lane, wave-uniform LDS base (lane*16 applied by HW)
DI void gload_lds16(const u16* g, u16* l) {
  __builtin_amdgcn_global_load_lds(
      (const __attribute__((address_space(1))) uint32_t*)g,
      (__attribute__((address_space(3))) uint32_t*)l,
      16, 0, 0);
}

// ---------------------------------------------------------------------------
// Transpose + f32->bf16 convert:  in[r][c] (ld=ldin)  ->  out[c][r] (ld=ldout)
// grid = (rows/64, cols/64), block = 256
// ---------------------------------------------------------------------------
__global__ __launch_bounds__(256)
void transpose_cvt_k(const float* __restrict__ in, int ldin,
                     u16* __restrict__ out, int ldout)
{
  __shared__ float tile[64][65];
  const int r0 = blockIdx.x * 64;
  const int c0 = blockIdx.y * 64;
  const int t  = threadIdx.x;
  const int r4 = t >> 6, c = t & 63;
#pragma unroll
  for (int i = 0; i < 16; ++i) {
    int rr = r4 + i * 4;
    tile[rr][c] = in[(size_t)(r0 + rr) * ldin + c0 + c];
  }
  __syncthreads();
#pragma unroll
  for (int i = 0; i < 16; ++i) {
    int rr = r4 + i * 4;
    out[(size_t)(c0 + rr) * ldout + r0 + c] = f2bf(tile[c][rr]);
  }
}

// ---------------------------------------------------------------------------
// LoRA-A weight transpose: W f32 [K][16] -> Wt bf16 [16][K].  grid=K/64
// ---------------------------------------------------------------------------
__global__ __launch_bounds__(256)
void lora_wt_k(const float* __restrict__ W, int K, u16* __restrict__ Wt)
{
  __shared__ float tile[64][17];
  const int k0 = blockIdx.x * 64;
  const int t = threadIdx.x;
  const int lr = t >> 2, lc = (t & 3) * 4;
  float4 v = *(const float4*)(W + (size_t)(k0 + lr) * 16 + lc);
  tile[lr][lc + 0] = v.x; tile[lr][lc + 1] = v.y;
  tile[lr][lc + 2] = v.z; tile[lr][lc + 3] = v.w;
  __syncthreads();
  const int r = t >> 4, kk = (t & 15) * 4;
  s16x4 o;
#pragma unroll
  for (int j = 0; j < 4; ++j) o[j] = (short)f2bf(tile[kk + j][r]);
  *(s16x4*)(Wt + (size_t)r * K + k0 + kk) = o;
}

// ---------------------------------------------------------------------------
// RMSNorm: x f32 [S][HID] -> out bf16 [S][HID].  grid=S, block=256
// ---------------------------------------------------------------------------
__global__ __launch_bounds__(256)
void rmsnorm_k(const float* __restrict__ x, const float* __restrict__ w,
               u16* __restrict__ out)
{
  const int m = blockIdx.x, t = threadIdx.x;
  const float* xr = x + (size_t)m * HID_;
  float4 a = *(const float4*)(xr + t * 8);
  float4 b = *(const float4*)(xr + t * 8 + 4);
  float v[8] = {a.x, a.y, a.z, a.w, b.x, b.y, b.z, b.w};
  float ss = 0.f;
#pragma unroll
  for (int e = 0; e < 8; ++e) ss += v[e] * v[e];
#pragma unroll
  for (int off = 32; off; off >>= 1) ss += __shfl_xor(ss, off);
  __shared__ float sm[4];
  if ((t & 63) == 0) sm[t >> 6] = ss;
  __syncthreads();
  const float tot = sm[0] + sm[1] + sm[2] + sm[3];
  const float sc = rsqrtf(tot * (1.0f / HID_) + 1e-6f);
  const float* wr = w + t * 8;
  s16x8 ov;
#pragma unroll
  for (int e = 0; e < 8; ++e) ov[e] = (short)f2bf(v[e] * sc * wr[e]);
  *(s16x8*)(out + (size_t)m * HID_ + t * 8) = ov;
}

// ---------------------------------------------------------------------------
// LoRA-A / gate-logits: out[m][r] = sum_k A_bf16[m][k]*Wt[r][k] + b[r], r<16
// Wt is [16][K] bf16 (pre-transposed).  grid = M, block = 256.
// Thread t owns k-slice [c*2048 + t*8, +8) -> all loads coalesced 16B/lane.
// ---------------------------------------------------------------------------
__global__ __launch_bounds__(256)
void lora_a_k(const u16* __restrict__ A, int K,
              const u16* __restrict__ Wt, const float* __restrict__ b,
              float* __restrict__ out)
{
  const int m = blockIdx.x, t = threadIdx.x;
  const u16* ar = A + (size_t)m * K;
  float acc[16];
#pragma unroll
  for (int r = 0; r < 16; ++r) acc[r] = 0.f;
  for (int c = 0; c < K; c += 2048) {
    const int kb = c + t * 8;
    s16x8 av = *(const s16x8*)(ar + kb);
    float a[8];
#pragma unroll
    for (int e = 0; e < 8; ++e) a[e] = bf2f((u16)av[e]);
#pragma unroll
    for (int r = 0; r < 16; ++r) {
      s16x8 wv = *(const s16x8*)(Wt + (size_t)r * K + kb);
#pragma unroll
      for (int e = 0; e < 8; ++e) acc[r] += a[e] * bf2f((u16)wv[e]);
    }
  }
#pragma unroll
  for (int r = 0; r < 16; ++r)
#pragma unroll
    for (int off = 32; off; off >>= 1) acc[r] += __shfl_xor(acc[r], off);
  __shared__ float sm[64];
  if ((t & 63) == 0) {
#pragma unroll
    for (int r = 0; r < 16; ++r) sm[(t >> 6) * 16 + r] = acc[r];
  }
  __syncthreads();
  if (t < 16)
    out[(size_t)m * 16 + t] = sm[t] + sm[16 + t] + sm[32 + t] + sm[48 + t] + b[t];
}

// ---------------------------------------------------------------------------
// GEMM: C[M][N] = A_bf16[M][K] @ B (Bt = B^T bf16 [N][K]) + bias
//       + 2*(lt[M][16] @ lbw[16][N] + lbb)  (+ res[M][N])
// tile 128 x BN, BK=64, 4 waves.
// Staging: global_load_lds x16B, linear LDS dest, PRE-SWIZZLED global source
// (chunk slot = (lane&7)^(lane>>3)); read side uses slot^(row&7) -> both
// permutations match (rule #21), ds_read_b128 is bank-conflict-free.
// ---------------------------------------------------------------------------
template<int BN, bool OUT_BF, bool HAS_RES>
__global__ __launch_bounds__(256)
void gemm_k(const u16* __restrict__ A, const u16* __restrict__ Bt,
            const float* __restrict__ bias,
            const float* __restrict__ lt, const float* __restrict__ lbw,
            const float* __restrict__ lbb,
            const float* __restrict__ res, void* __restrict__ outp,
            int N, int K)
{
  constexpr int BM = 128, BK = 64;
  constexpr int NJ = BN / 32;                 // n-frags per wave
  constexpr int BCW = BN / 32;                // B chunks per wave (4 or 2)
  __shared__ u16 Asm[BM * BK];
  __shared__ u16 Bsm[BN * BK];
  const int tid = threadIdx.x;
  const int lane = tid & 63;
  const int w = tid >> 6;
  const int l15 = lane & 15, g = lane >> 4;

  // XCD-aware bijective block swizzle (all grids have nwg % 8 == 0):
  const int nwg = gridDim.x * gridDim.y;
  const int linear = blockIdx.y * gridDim.x + blockIdx.x;
  const int tile = (linear & 7) * (nwg >> 3) + (linear >> 3);
  const int bx = tile % gridDim.x;
  const int by = tile / gridDim.x;
  const int m0 = by * BM, n0 = bx * BN;
  const int rm = (w >> 1) * 64, rn = (w & 1) * (BN / 2);

  f32x4 acc[4][NJ];
#pragma unroll
  for (int i = 0; i < 4; ++i)
#pragma unroll
    for (int j = 0; j < NJ; ++j) acc[i][j] = (f32x4){0.f, 0.f, 0.f, 0.f};

  // LoRA rank-16 contribution as one MFMA k-step (k 0..15 real, 16..31 zero).
  {
    s16x8 la[4], lb[NJ];
#pragma unroll
    for (int i = 0; i < 4; ++i) {
      s16x8 v = {0, 0, 0, 0, 0, 0, 0, 0};
      if (g < 2) {
        const float* tp = lt + (size_t)(m0 + rm + i * 16 + l15) * 16 + g * 8;
#pragma unroll
        for (int e = 0; e < 8; ++e) v[e] = (short)f2bf(2.0f * tp[e]);
      }
      la[i] = v;
    }
#pragma unroll
    for (int j = 0; j < NJ; ++j) {
      s16x8 v = {0, 0, 0, 0, 0, 0, 0, 0};
      if (g < 2) {
        const int n = n0 + rn + j * 16 + l15;
#pragma unroll
        for (int e = 0; e < 8; ++e) v[e] = (short)f2bf(lbw[(size_t)(g * 8 + e) * N + n]);
      }
      lb[j] = v;
    }
#pragma unroll
    for (int i = 0; i < 4; ++i)
#pragma unroll
      for (int j = 0; j < NJ; ++j) acc[i][j] = MFMA(la[i], lb[j], acc[i][j]);
  }

  // Staging geometry: 1 KiB chunk = 8 rows x 64 u16. A: 16 chunks, 4/wave.
  const int srow  = lane >> 3;
  const int sslot = (lane & 7) ^ srow;
  const u16* Aga[4];
  u16* Alds[4];
#pragma unroll
  for (int c = 0; c < 4; ++c) {
    const int ch = w * 4 + c;
    Aga[c]  = A + (size_t)(m0 + ch * 8 + srow) * K + sslot * 8;
    Alds[c] = Asm + ch * 512;
  }
  const u16* Bga[BCW];
  u16* Blds[BCW];
#pragma unroll
  for (int c = 0; c < BCW; ++c) {
    const int ch = w * BCW + c;
    Bga[c]  = Bt + (size_t)(n0 + ch * 8 + srow) * K + sslot * 8;
    Blds[c] = Bsm + ch * 512;
  }

  const int nk = K / BK;
  for (int kt = 0; kt < nk; ++kt) {
    const int ko = kt * BK;
    __syncthreads();                       // all waves done reading LDS
#pragma unroll
    for (int c = 0; c < 4; ++c)   gload_lds16(Aga[c] + ko, Alds[c]);
#pragma unroll
    for (int c = 0; c < BCW; ++c) gload_lds16(Bga[c] + ko, Blds[c]);
    __syncthreads();                       // vmcnt(0) drain + barrier: LDS ready
#pragma unroll
    for (int ks = 0; ks < 2; ++ks) {
      s16x8 af[4], bfv[NJ];
#pragma unroll
      for (int i = 0; i < 4; ++i) {
        int r = rm + i * 16 + l15;
        af[i] = *(const s16x8*)(Asm + r * BK + (((ks * 4 + g) ^ (r & 7)) * 8));
      }
#pragma unroll
      for (int j = 0; j < NJ; ++j) {
        int r = rn + j * 16 + l15;
        bfv[j] = *(const s16x8*)(Bsm + r * BK + (((ks * 4 + g) ^ (r & 7)) * 8));
      }
#pragma unroll
      for (int i = 0; i < 4; ++i)
#pragma unroll
        for (int j = 0; j < NJ; ++j) acc[i][j] = MFMA(af[i], bfv[j], acc[i][j]);
    }
  }

  // epilogue: + bias + 2*lbb (+res); C/D layout: row=(lane>>4)*4+reg, col=lane&15
#pragma unroll
  for (int j = 0; j < NJ; ++j) {
    const int n = n0 + rn + j * 16 + l15;
    const float bt = bias[n] + 2.0f * lbb[n];
#pragma unroll
    for (int i = 0; i < 4; ++i) {
      const int mb = m0 + rm + i * 16 + g * 4;
#pragma unroll
      for (int reg = 0; reg < 4; ++reg) {
        const size_t o = (size_t)(mb + reg) * N + n;
        float v = acc[i][j][reg] + bt;
        if (HAS_RES) v += res[o];
        if (OUT_BF) ((u16*)outp)[o] = f2bf(v);
        else        ((float*)outp)[o] = v;
      }
    }
  }
}

// ---------------------------------------------------------------------------
// RoPE for q and k: qkv f32 [S][3072] -> qr bf16 [16][S][128], kr bf16 [4][S][128]
// grid = S, block = 256
// ---------------------------------------------------------------------------
__global__ __launch_bounds__(256)
void rope_k(const float* __restrict__ qkv,
            u16* __restrict__ qr, u16* __restrict__ kr)
{
  const int s = blockIdx.x, t = threadIdx.x;
  const float* row = qkv + (size_t)s * QKV_;
#pragma unroll
  for (int p = t; p < 1280; p += 256) {   // 16*64 q-pairs + 4*64 k-pairs
    const int head = p >> 6;
    const int i = p & 63;
    const float freq = expf(-(float)i * (9.210340371976184f / 64.0f));
    const float ang = (float)s * freq;
    float sn, cs;
    sincosf(ang, &sn, &cs);
    int col; u16* dst;
    if (head < QH_) {
      col = head * HD_ + 2 * i;
      dst = qr + ((size_t)head * S_ + s) * HD_ + 2 * i;
    } else {
      const int kh = head - QH_;
      col = QH_ * HD_ + kh * HD_ + 2 * i;
      dst = kr + ((size_t)kh * S_ + s) * HD_ + 2 * i;
    }
    const float x0 = row[col], x1 = row[col + 1];
    const float y0 = x0 * cs - x1 * sn;
    const float y1 = x1 * cs + x0 * sn;
    uint32_t pack = (uint32_t)f2bf(y0) | ((uint32_t)f2bf(y1) << 16);
    *(uint32_t*)dst = pack;
  }
}

// ---------------------------------------------------------------------------
// Flash attention, causal, GQA. 1 wave per (head, 16 q-rows). KVBLK=32.
// Writes gated, normalized output directly as bf16 [S][HID].
// ---------------------------------------------------------------------------
__global__ __launch_bounds__(64, 2)
void attn_k(const u16* __restrict__ qr, const u16* __restrict__ kr,
            const u16* __restrict__ vT, const float* __restrict__ glog,
            u16* __restrict__ valg)
{
  const int h = blockIdx.x, qb = blockIdx.y;
  const int kvh = h >> 2;
  const int lane = threadIdx.x;
  const int l15 = lane & 15, g = lane >> 4;
  const int q0 = qb * 16;
  __shared__ u16 P[16 * 40];    // [16 q][32 kv], padded to 40 (80B rows)

  s16x8 qf[4];
  const u16* qbase = qr + ((size_t)h * S_ + q0 + l15) * HD_ + g * 8;
#pragma unroll
  for (int st = 0; st < 4; ++st) qf[st] = *(const s16x8*)(qbase + st * 32);

  f32x4 oacc[8];
#pragma unroll
  for (int t = 0; t < 8; ++t) oacc[t] = (f32x4){0.f, 0.f, 0.f, 0.f};
  float mrun[4], lrun[4];
#pragma unroll
  for (int r = 0; r < 4; ++r) { mrun[r] = -INFINITY; lrun[r] = 0.f; }

  const u16* krh = kr + (size_t)kvh * S_ * HD_;
  const u16* vth = vT + (size_t)kvh * HD_ * S_;
  const int ktiles = (q0 + 15) / 32 + 1;

  for (int kt = 0; kt < ktiles; ++kt) {
    const int kvb = kt * 32;
    f32x4 s0v = (f32x4){0.f, 0.f, 0.f, 0.f}, s1v = s0v;
#pragma unroll
    for (int st = 0; st < 4; ++st) {
      s16x8 k0 = *(const s16x8*)(krh + (size_t)(kvb + l15) * HD_ + st * 32 + g * 8);
      s16x8 k1 = *(const s16x8*)(krh + (size_t)(kvb + 16 + l15) * HD_ + st * 32 + g * 8);
      s0v = MFMA(qf[st], k0, s0v);
      s1v = MFMA(qf[st], k1, s1v);
    }
    float p0[4], p1[4], mx[4];
#pragma unroll
    for (int r = 0; r < 4; ++r) {
      const int q = q0 + g * 4 + r;
      float a = s0v[r] * SCL_; if (kvb + l15 > q)      a = -1e30f;
      float b = s1v[r] * SCL_; if (kvb + 16 + l15 > q) b = -1e30f;
      p0[r] = a; p1[r] = b; mx[r] = fmaxf(a, b);
    }
#pragma unroll
    for (int r = 0; r < 4; ++r) {
#pragma unroll
      for (int off = 1; off < 16; off <<= 1)
        mx[r] = fmaxf(mx[r], __shfl_xor(mx[r], off));
    }
    float alpha[4];
#pragma unroll
    for (int r = 0; r < 4; ++r) {
      const float mn = fmaxf(mrun[r], mx[r]);
      alpha[r] = expf(mrun[r] - mn);
      const float e0 = expf(p0[r] - mn), e1 = expf(p1[r] - mn);
      p0[r] = e0; p1[r] = e1;
      float ps = e0 + e1;
#pragma unroll
      for (int off = 1; off < 16; off <<= 1) ps += __shfl_xor(ps, off);
      lrun[r] = lrun[r] * alpha[r] + ps;
      mrun[r] = mn;
    }
#pragma unroll
    for (int t = 0; t < 8; ++t)
#pragma unroll
      for (int r = 0; r < 4; ++r) oacc[t][r] *= alpha[r];
    __syncthreads();
#pragma unroll
    for (int r = 0; r < 4; ++r) {
      P[(g * 4 + r) * 40 + l15]      = f2bf(p0[r]);
      P[(g * 4 + r) * 40 + 16 + l15] = f2bf(p1[r]);
    }
    __syncthreads();
    const s16x8 pav = *(const s16x8*)(P + l15 * 40 + g * 8);
#pragma unroll
    for (int t = 0; t < 8; ++t) {
      s16x8 vf = *(const s16x8*)(vth + (size_t)(t * 16 + l15) * S_ + kvb + g * 8);
      oacc[t] = MFMA(pav, vf, oacc[t]);
    }
  }
  float fac[4];
#pragma unroll
  for (int r = 0; r < 4; ++r) {
    const int q = q0 + g * 4 + r;
    const float lg = glog[(size_t)q * 16 + h];
    fac[r] = (1.0f / (1.0f + expf(-lg))) / lrun[r];
  }
#pragma unroll
  for (int t = 0; t < 8; ++t)
#pragma unroll
    for (int r = 0; r < 4; ++r)
      valg[(size_t)(q0 + g * 4 + r) * HID_ + h * HD_ + t * 16 + l15] =
          f2bf(oacc[t][r] * fac[r]);
}

// ---------------------------------------------------------------------------
// gelu(tanh)(gate) * up :  gu bf16 [S][16384] -> hff bf16 [S][8192]
// grid = (4, S), block = 256
// ---------------------------------------------------------------------------
__global__ __launch_bounds__(256)
void gelu_mul_k(const u16* __restrict__ gu, u16* __restrict__ hff)
{
  const int m = blockIdx.y;
  const int j0 = (blockIdx.x * 256 + threadIdx.x) * 8;
  const u16* gp = gu + (size_t)m * GU2_ + j0;
  s16x8 gv = *(const s16x8*)gp;
  s16x8 uv = *(const s16x8*)(gp + FF_);
  s16x8 ov;
#pragma unroll
  for (int e = 0; e < 8; ++e) {
    const float gx = bf2f((u16)gv[e]);
    const float ux = bf2f((u16)uv[e]);
    const float inner = 0.7978845608028654f * (gx + 0.044715f * gx * gx * gx);
    const float hv = 0.5f * gx * (1.0f + tanhf(inner));
    ov[e] = (short)f2bf(hv * ux);
  }
  *(s16x8*)(hff + (size_t)m * FF_ + j0) = ov;
}

// ---------------------------------------------------------------------------
// host-side launch
// ---------------------------------------------------------------------------
extern "C" void kernel_launch(void* const* d_in, const int* in_sizes, int n_in,
                              void* d_out, int out_size, void* d_ws, size_t ws_size,
                              hipStream_t stream)
{
  (void)in_sizes; (void)n_in; (void)out_size; (void)ws_size;
  const float* x     = (const float*)d_in[0];
  const float* n1w   = (const float*)d_in[2];
  const float* n2w   = (const float*)d_in[3];
  const float* qkv_w = (const float*)d_in[4];
  const float* qkv_b = (const float*)d_in[5];
  const float* lqa_w = (const float*)d_in[6];
  const float* lqa_b = (const float*)d_in[7];
  const float* lqb_w = (const float*)d_in[8];
  const float* lqb_b = (const float*)d_in[9];
  const float* o_w   = (const float*)d_in[10];
  const float* o_b   = (const float*)d_in[11];
  const float* loa_w = (const float*)d_in[12];
  const float* loa_b = (const float*)d_in[13];
  const float* lob_w = (const float*)d_in[14];
  const float* lob_b = (const float*)d_in[15];
  const float* gate_w= (const float*)d_in[16];
  const float* gate_b= (const float*)d_in[17];
  const float* gu_w  = (const float*)d_in[18];
  const float* gu_b  = (const float*)d_in[19];
  const float* lga_w = (const float*)d_in[20];
  const float* lga_b = (const float*)d_in[21];
  const float* lgb_w = (const float*)d_in[22];
  const float* lgb_b = (const float*)d_in[23];
  const float* dn_w  = (const float*)d_in[24];
  const float* dn_b  = (const float*)d_in[25];
  const float* lda_w = (const float*)d_in[26];
  const float* lda_b = (const float*)d_in[27];
  const float* ldb_w = (const float*)d_in[28];
  const float* ldb_b = (const float*)d_in[29];

  char* ws = (char*)d_ws;
  constexpr size_t OFF_XN   = 0;                       // bf16 [2048][2048]
  constexpr size_t OFF_WTQ  = OFF_XN   + 8388608;      // bf16 [3072][2048]
  constexpr size_t OFF_WTO  = OFF_WTQ  + 12582912;     // bf16 [2048][2048]
  constexpr size_t OFF_WTG  = OFF_WTO  + 8388608;      // bf16 [16384][2048]
  constexpr size_t OFF_WTD  = OFF_WTG  + 67108864;     // bf16 [2048][8192]
  constexpr size_t OFF_QKV  = OFF_WTD  + 33554432;     // f32  [2048][3072]
  constexpr size_t OFF_QR   = OFF_QKV  + 25165824;     // bf16 [16][2048][128]
  constexpr size_t OFF_KR   = OFF_QR   + 8388608;      // bf16 [4][2048][128]
  constexpr size_t OFF_VT   = OFF_KR   + 2097152;      // bf16 [4][128][2048]
  constexpr size_t OFF_VALG = OFF_VT   + 2097152;      // bf16 [2048][2048]
  constexpr size_t OFF_GU   = OFF_VALG + 8388608;      // bf16 [2048][16384]
  constexpr size_t OFF_HN   = OFF_GU   + 67108864;     // bf16 [2048][2048]
  constexpr size_t OFF_HFF  = OFF_HN   + 8388608;      // bf16 [2048][8192]
  constexpr size_t OFF_TQKV = OFF_HFF  + 33554432;     // f32  [2048][16]
  constexpr size_t OFF_GLOG = OFF_TQKV + 131072;
  constexpr size_t OFF_TO   = OFF_GLOG + 131072;
  constexpr size_t OFF_TGU  = OFF_TO   + 131072;
  constexpr size_t OFF_TDN  = OFF_TGU  + 131072;
  // pre-transposed LoRA-A / gate weights, bf16 [16][K]
  constexpr size_t OFF_LQAT = OFF_TDN  + 131072;       // [16][2048]
  constexpr size_t OFF_GATT = OFF_LQAT + 65536;        // [16][2048]
  constexpr size_t OFF_LOAT = OFF_GATT + 65536;        // [16][2048]
  constexpr size_t OFF_LGAT = OFF_LOAT + 65536;        // [16][2048]
  constexpr size_t OFF_LDAT = OFF_LGAT + 65536;        // [16][8192]

  u16*   xn   = (u16*)(ws + OFF_XN);
  u16*   wtq  = (u16*)(ws + OFF_WTQ);
  u16*   wto  = (u16*)(ws + OFF_WTO);
  u16*   wtg  = (u16*)(ws + OFF_WTG);
  u16*   wtd  = (u16*)(ws + OFF_WTD);
  float* qkv  = (float*)(ws + OFF_QKV);
  u16*   qr   = (u16*)(ws + OFF_QR);
  u16*   kr   = (u16*)(ws + OFF_KR);
  u16*   vt   = (u16*)(ws + OFF_VT);
  u16*   valg = (u16*)(ws + OFF_VALG);
  u16*   gub  = (u16*)(ws + OFF_GU);
  u16*   hn   = (u16*)(ws + OFF_HN);
  u16*   hff  = (u16*)(ws + OFF_HFF);
  float* tqkv = (float*)(ws + OFF_TQKV);
  float* glog = (float*)(ws + OFF_GLOG);
  float* t_o  = (float*)(ws + OFF_TO);
  float* t_gu = (float*)(ws + OFF_TGU);
  float* t_dn = (float*)(ws + OFF_TDN);
  u16*   lqat = (u16*)(ws + OFF_LQAT);
  u16*   gatt = (u16*)(ws + OFF_GATT);
  u16*   loat = (u16*)(ws + OFF_LOAT);
  u16*   lgat = (u16*)(ws + OFF_LGAT);
  u16*   ldat = (u16*)(ws + OFF_LDAT);

  // weight transpose + bf16 convert
  transpose_cvt_k<<<dim3(32, 48),  256, 0, stream>>>(qkv_w, QKV_, wtq, HID_);
  transpose_cvt_k<<<dim3(32, 32),  256, 0, stream>>>(o_w,   HID_, wto, HID_);
  transpose_cvt_k<<<dim3(32, 256), 256, 0, stream>>>(gu_w,  GU2_, wtg, HID_);
  transpose_cvt_k<<<dim3(128, 32), 256, 0, stream>>>(dn_w,  HID_, wtd, FF_);
  // lora-A / gate weight transpose (f32 [K][16] -> bf16 [16][K])
  lora_wt_k<<<32,  256, 0, stream>>>(lqa_w,  HID_, lqat);
  lora_wt_k<<<32,  256, 0, stream>>>(gate_w, HID_, gatt);
  lora_wt_k<<<32,  256, 0, stream>>>(loa_w,  HID_, loat);
  lora_wt_k<<<32,  256, 0, stream>>>(lga_w,  HID_, lgat);
  lora_wt_k<<<128, 256, 0, stream>>>(lda_w,  FF_,  ldat);

  // attention branch
  rmsnorm_k<<<S_, 256, 0, stream>>>(x, n1w, xn);
  lora_a_k<<<S_, 256, 0, stream>>>(xn, HID_, lqat, lqa_b, tqkv);
  lora_a_k<<<S_, 256, 0, stream>>>(xn, HID_, gatt, gate_b, glog);
  gemm_k<64, false, false><<<dim3(48, 16), 256, 0, stream>>>(
      xn, wtq, qkv_b, tqkv, lqb_w, lqb_b, nullptr, qkv, QKV_, HID_);
  rope_k<<<S_, 256, 0, stream>>>(qkv, qr, kr);
  transpose_cvt_k<<<dim3(32, 8), 256, 0, stream>>>(qkv + 2560, QKV_, vt, S_);
  attn_k<<<dim3(QH_, S_ / 16), 64, 0, stream>>>(qr, kr, vt, glog, valg);
  lora_a_k<<<S_, 256, 0, stream>>>(valg, HID_, loat, loa_b, t_o);
  gemm_k<64, false, true><<<dim3(32, 16), 256, 0, stream>>>(
      valg, wto, o_b, t_o, lob_w, lob_b, x, d_out, HID_, HID_);  // h -> d_out

  // feedforward branch
  rmsnorm_k<<<S_, 256, 0, stream>>>((const float*)d_out, n2w, hn);
  lora_a_k<<<S_, 256, 0, stream>>>(hn, HID_, lgat, lga_b, t_gu);
  gemm_k<128, true, false><<<dim3(128, 16), 256, 0, stream>>>(
      hn, wtg, gu_b, t_gu, lgb_w, lgb_b, nullptr, gub, GU2_, HID_);
  gelu_mul_k<<<dim3(4, S_), 256, 0, stream>>>(gub, hff);
  lora_a_k<<<S_, 256, 0, stream>>>(hff, FF_, ldat, lda_b, t_dn);
  gemm_k<64, false, true><<<dim3(32, 16), 256, 0, stream>>>(
      hff, wtd, dn_b, t_dn, ldb_w, ldb_b, (const float*)d_out, d_out, HID_, FF_);
}